// Round 5
// baseline (116.649 us; speedup 1.0000x reference)
//
#include <hip/hip_runtime.h>

#define HH 192
#define WW 192
#define VV 1024
#define FF 2048
#define SIG 0.01f
#define EPSF 1e-7f
#define LOG2E 1.4426950408889634f
#define BAND_T 15.0f                 // |arg| threshold (log2 units) for exact eval
#define C_OUT 1.4426943e-7f          // log2(1+EPSF)
#define C_IN  (-23.2534966642f)      // log2(EPSF)
#define NTILE 576                    // 24x24 tiles of 8x8 px

// Single fused kernel: block = tile (4 waves). Each block:
//  1) projects all 1024 vertices into LDS (redundant per block, ~trivial)
//  2) per wave, 8 rounds x 64 faces: per-lane coefficient build + interval
//     classification; wave-uniform readlane eval loop for band faces
//  3) cross-wave LDS reduce -> image -> squared diff -> one atomicAdd(out)
// No workspace usage at all.
__global__ void __launch_bounds__(256)
fused_kernel(const float* __restrict__ verts, const int* __restrict__ faces,
             const float* __restrict__ ref, const float* __restrict__ cam,
             float* __restrict__ out) {
    __shared__ float sx[VV], sy[VV];
    __shared__ float red[4][64];
    const int tid = threadIdx.x;

    // camera basis (uniform, ~20 scalar ops)
    const float cx = cam[0], cy = cam[1], cz = cam[2];
    const float nrm = sqrtf(cx*cx + cy*cy + cz*cz);
    const float inv = 1.0f / fmaxf(nrm, 1e-8f);
    const float zx = -cx*inv, zy = -cy*inv, zz = -cz*inv;
    float xx = zz, xz = -zx;
    const float invx = 1.0f / fmaxf(sqrtf(xx*xx + xz*xz), 1e-8f);
    xx *= invx; xz *= invx;
    const float yx = zy*xz, yy = zz*xx - zx*xz, yz = -zy*xx;
    const float ratio = 0.57735026918962576f;   // tan(30 deg)

    for (int i = tid; i < VV; i += 256) {
        const float vx = verts[3*i+0] - cx;
        const float vy = verts[3*i+1] - cy;
        const float vz = verts[3*i+2] - cz;
        const float pcx = xx*vx + xz*vz;
        const float pcy = yx*vx + yy*vy + yz*vz;
        float pcz = zx*vx + zy*vy + zz*vz;
        pcz = fmaxf(pcz, 1e-5f);
        const float iz = 1.0f / (pcz * ratio);
        sx[i] = pcx * iz;
        sy[i] = pcy * iz;
    }
    __syncthreads();

    const int t = blockIdx.x, tx = t % 24, ty = t / 24;
    const int w = tid >> 6, l = tid & 63;
    const int x = tx*8 + (l & 7), y = ty*8 + (l >> 3);
    const float px = (x + 0.5f) * (2.0f/WW) - 1.0f;
    const float py = 1.0f - (y + 0.5f) * (2.0f/HH);
    const float xc = (tx*8 + 4.0f) * (2.0f/WW) - 1.0f;
    const float yc = 1.0f - (ty*8 + 4.0f) * (2.0f/HH);
    const float hx = 3.5f * (2.0f/WW), hy = 3.5f * (2.0f/HH);
    const float dIn = C_IN - C_OUT;
    const float kk = -(LOG2E / SIG);

    float acc = 512.0f * C_OUT;          // baseline: this wave's 512 faces outside
    for (int r = 0; r < 8; ++r) {
        const int f = (w*8 + r)*64 + l;  // this lane's face
        const int i0 = faces[3*f+0], i1 = faces[3*f+1], i2 = faces[3*f+2];
        const float p0x = sx[i0], p0y = sy[i0];
        const float p1x = sx[i1], p1y = sy[i1];
        const float p2x = sx[i2], p2y = sy[i2];
        const float e0x = p1x-p0x, e0y = p1y-p0y;
        const float e1x = p2x-p1x, e1y = p2y-p1y;
        const float e2x = p0x-p2x, e2y = p0y-p2y;
        const float c0 = e0y*p0x - e0x*p0y;
        const float c1 = e1y*p1x - e1x*p1y;
        const float c2 = e2y*p2x - e2x*p2y;
        const float area2 = e0x*(p2y-p0y) - e0y*(p2x-p0x);
        const float sgn = (area2 >= 0.0f) ? kk : -kk;
        // m_i = kk*sgn' / elen  via rsq of clamped squared length
        const float m0 = sgn * __builtin_amdgcn_rsqf(fmaxf(e0x*e0x+e0y*e0y, 1e-16f));
        const float m1 = sgn * __builtin_amdgcn_rsqf(fmaxf(e1x*e1x+e1y*e1y, 1e-16f));
        const float m2 = sgn * __builtin_amdgcn_rsqf(fmaxf(e2x*e2x+e2y*e2y, 1e-16f));
        const float A0 = m0*e0x, B0 = -m0*e0y, C0 = m0*c0;
        const float A1 = m1*e1x, B1 = -m1*e1y, C1 = m1*c1;
        const float A2 = m2*e2x, B2 = -m2*e2y, C2 = m2*c2;
        // interval classification over the tile
        const float ac0 = fmaf(A0, yc, fmaf(B0, xc, C0));
        const float ac1 = fmaf(A1, yc, fmaf(B1, xc, C1));
        const float ac2 = fmaf(A2, yc, fmaf(B2, xc, C2));
        const float sp0 = fmaf(fabsf(A0), hy, fabsf(B0)*hx);
        const float sp1 = fmaf(fabsf(A1), hy, fabsf(B1)*hx);
        const float sp2 = fmaf(fabsf(A2), hy, fabsf(B2)*hx);
        const bool skip = (ac0 - sp0 >= BAND_T) || (ac1 - sp1 >= BAND_T) || (ac2 - sp2 >= BAND_T);
        const bool deep = (ac0 + sp0 <= -BAND_T) && (ac1 + sp1 <= -BAND_T) && (ac2 + sp2 <= -BAND_T);
        acc += (float)__popcll(__ballot(deep)) * dIn;

        unsigned long long mb = __ballot(!skip && !deep);
        float prod = 1.0f;
        int cnt = 0;
        while (mb) {                     // wave-uniform loop over band faces
            const int src = __builtin_ctzll(mb); mb &= mb - 1;
#define RL(v) __int_as_float(__builtin_amdgcn_readlane(__float_as_int(v), src))
            const float a0 = fmaf(RL(A0), py, fmaf(RL(B0), px, RL(C0)));
            const float a1 = fmaf(RL(A1), py, fmaf(RL(B1), px, RL(C1)));
            const float a2 = fmaf(RL(A2), py, fmaf(RL(B2), px, RL(C2)));
#undef RL
            const float t0 = __builtin_amdgcn_exp2f(a0);
            const float t1 = __builtin_amdgcn_exp2f(a1);
            const float t2 = __builtin_amdgcn_exp2f(a2);
            const float P = (1.0f + t0) * (1.0f + t1) * (1.0f + t2);
            prod *= (1.0f + EPSF) - __builtin_amdgcn_rcpf(P);   // in [eps, 1+eps]
            if (++cnt == 4) {            // batched log2 (prod >= 1e-28, normal)
                acc += __builtin_amdgcn_logf(prod);
                prod = 1.0f; cnt = 0;
            }
        }
        if (cnt) acc += __builtin_amdgcn_logf(prod);
    }

    // cross-wave reduction: same lane l in all 4 waves = same pixel
    red[w][l] = acc;
    __syncthreads();
    if (w == 0) {
        const float S = red[0][l] + red[1][l] + red[2][l] + red[3][l];
        const float img = 1.0f - __builtin_amdgcn_exp2f(S);
        const float d = ref[y*WW + x] - img;
        float sq = d * d;
        #pragma unroll
        for (int off = 32; off > 0; off >>= 1)
            sq += __shfl_down(sq, off, 64);
        if (l == 0) {
            const float factor = 1.0f + fmaxf(6.0f - nrm, 0.0f);
            atomicAdd(out, sq * factor);
        }
    }
}

extern "C" void kernel_launch(void* const* d_in, const int* in_sizes, int n_in,
                              void* d_out, int out_size, void* d_ws, size_t ws_size,
                              hipStream_t stream) {
    const float* verts = (const float*)d_in[0];   // (1,1024,3) f32
    const int*   faces = (const int*)d_in[1];     // (1,2048,3) i32
    const float* ref   = (const float*)d_in[2];   // (192,192) f32
    const float* cam   = (const float*)d_in[3];   // (3,) f32
    float* out = (float*)d_out;

    hipMemsetAsync(d_out, 0, sizeof(float), stream);
    fused_kernel<<<NTILE, 256, 0, stream>>>(verts, faces, ref, cam, out);
}

// Round 6
// 91.747 us; speedup vs baseline: 1.2714x; 1.2714x over previous
//
#include <hip/hip_runtime.h>

#define HH 192
#define WW 192
#define VV 1024
#define FF 2048
#define NPIX (HH*WW)
#define SIG 0.01f
#define EPSF 1e-7f
#define LOG2E 1.4426950408889634f
#define BAND_T 15.0f                 // |arg| threshold (log2 units) for exact eval
#define C_OUT 1.4426943e-7f          // log2(1+EPSF)
#define C_IN  (-23.2534966642f)      // log2(EPSF)
#define NTILE 576                    // 24x24 tiles of 8x8 px
#define NCH 32                       // 64-face chunks

// ws layout: part[c*NPIX + t*64 + l] — per-chunk per-pixel log2-miss partials
// (fully overwritten every call; no zeroing needed)

// One wave = one (tile, 64-face chunk): lane builds its face's edge coeffs
// in-register (global vertex fetch, L1-resident), interval-classifies the
// tile, then wave-uniform readlane eval of band faces. No LDS, no atomics.
__global__ void __launch_bounds__(256)
main_kernel(const float* __restrict__ verts, const int* __restrict__ faces,
            const float* __restrict__ cam, float* __restrict__ part,
            float* __restrict__ out) {
    const int t = blockIdx.x;                        // tile 0..575
    const int w = threadIdx.x >> 6, l = threadIdx.x & 63;
    const int c = blockIdx.y * 4 + w;                // chunk 0..31
    const int f = c * 64 + l;                        // this lane's face

    // camera basis (wave-uniform, ~25 ops)
    const float cx = cam[0], cy = cam[1], cz = cam[2];
    const float nrm = sqrtf(cx*cx + cy*cy + cz*cz);
    const float inv = 1.0f / fmaxf(nrm, 1e-8f);
    const float zx = -cx*inv, zy = -cy*inv, zz = -cz*inv;
    float xx = zz, xz = -zx;
    const float invx = 1.0f / fmaxf(sqrtf(xx*xx + xz*xz), 1e-8f);
    xx *= invx; xz *= invx;
    const float yx = zy*xz, yy = zz*xx - zx*xz, yz = -zy*xx;
    const float ratio = 0.57735026918962576f;        // tan(30 deg)

    // project this lane's 3 vertices (L1-resident gather: verts = 12 KB)
    const int i0 = faces[3*f+0], i1 = faces[3*f+1], i2 = faces[3*f+2];
    float P[3][2];
    #pragma unroll
    for (int k = 0; k < 3; ++k) {
        const int idx = (k == 0) ? i0 : (k == 1) ? i1 : i2;
        const float vx = verts[3*idx+0] - cx;
        const float vy = verts[3*idx+1] - cy;
        const float vz = verts[3*idx+2] - cz;
        const float pcx = xx*vx + xz*vz;
        const float pcy = yx*vx + yy*vy + yz*vz;
        float pcz = zx*vx + zy*vy + zz*vz;
        pcz = fmaxf(pcz, 1e-5f);
        const float iz = 1.0f / (pcz * ratio);
        P[k][0] = pcx * iz;
        P[k][1] = pcy * iz;
    }
    const float p0x = P[0][0], p0y = P[0][1];
    const float p1x = P[1][0], p1y = P[1][1];
    const float p2x = P[2][0], p2y = P[2][1];
    const float e0x = p1x-p0x, e0y = p1y-p0y;
    const float e1x = p2x-p1x, e1y = p2y-p1y;
    const float e2x = p0x-p2x, e2y = p0y-p2y;
    const float c0 = e0y*p0x - e0x*p0y;
    const float c1 = e1y*p1x - e1x*p1y;
    const float c2 = e2y*p2x - e2x*p2y;
    const float area2 = e0x*(p2y-p0y) - e0y*(p2x-p0x);
    const float kk = -(LOG2E / SIG);
    const float sgn = (area2 >= 0.0f) ? kk : -kk;
    const float m0 = sgn * __builtin_amdgcn_rsqf(fmaxf(e0x*e0x+e0y*e0y, 1e-16f));
    const float m1 = sgn * __builtin_amdgcn_rsqf(fmaxf(e1x*e1x+e1y*e1y, 1e-16f));
    const float m2 = sgn * __builtin_amdgcn_rsqf(fmaxf(e2x*e2x+e2y*e2y, 1e-16f));
    const float A0 = m0*e0x, B0 = -m0*e0y, C0 = m0*c0;
    const float A1 = m1*e1x, B1 = -m1*e1y, C1 = m1*c1;
    const float A2 = m2*e2x, B2 = -m2*e2y, C2 = m2*c2;

    // tile geometry + interval classification
    const int tx = t % 24, ty = t / 24;
    const int x = tx*8 + (l & 7), y = ty*8 + (l >> 3);
    const float px = (x + 0.5f) * (2.0f/WW) - 1.0f;
    const float py = 1.0f - (y + 0.5f) * (2.0f/HH);
    const float xc = (tx*8 + 4.0f) * (2.0f/WW) - 1.0f;
    const float yc = 1.0f - (ty*8 + 4.0f) * (2.0f/HH);
    const float hx = 3.5f * (2.0f/WW), hy = 3.5f * (2.0f/HH);
    const float ac0 = fmaf(A0, yc, fmaf(B0, xc, C0));
    const float ac1 = fmaf(A1, yc, fmaf(B1, xc, C1));
    const float ac2 = fmaf(A2, yc, fmaf(B2, xc, C2));
    const float sp0 = fmaf(fabsf(A0), hy, fabsf(B0)*hx);
    const float sp1 = fmaf(fabsf(A1), hy, fabsf(B1)*hx);
    const float sp2 = fmaf(fabsf(A2), hy, fabsf(B2)*hx);
    const bool skip = (ac0 - sp0 >= BAND_T) || (ac1 - sp1 >= BAND_T) || (ac2 - sp2 >= BAND_T);
    const bool deep = (ac0 + sp0 <= -BAND_T) && (ac1 + sp1 <= -BAND_T) && (ac2 + sp2 <= -BAND_T);

    float acc = 64.0f * C_OUT
              + (float)__popcll(__ballot(deep)) * (C_IN - C_OUT);
    unsigned long long mb = __ballot(!skip && !deep);
    float prod = 1.0f;
    int cnt = 0;
    while (mb) {                         // wave-uniform loop over band faces
        const int src = __builtin_ctzll(mb); mb &= mb - 1;
#define RL(v) __int_as_float(__builtin_amdgcn_readlane(__float_as_int(v), src))
        const float a0 = fmaf(RL(A0), py, fmaf(RL(B0), px, RL(C0)));
        const float a1 = fmaf(RL(A1), py, fmaf(RL(B1), px, RL(C1)));
        const float a2 = fmaf(RL(A2), py, fmaf(RL(B2), px, RL(C2)));
#undef RL
        const float t0 = __builtin_amdgcn_exp2f(a0);
        const float t1 = __builtin_amdgcn_exp2f(a1);
        const float t2 = __builtin_amdgcn_exp2f(a2);
        const float Pr = (1.0f + t0) * (1.0f + t1) * (1.0f + t2);
        prod *= (1.0f + EPSF) - __builtin_amdgcn_rcpf(Pr);   // in [eps, 1+eps]
        if (++cnt == 4) {                // batched log2 (prod >= 1e-28, normal)
            acc += __builtin_amdgcn_logf(prod) - 4.0f*C_OUT;
            prod = 1.0f; cnt = 0;
        }
    }
    if (cnt) acc += __builtin_amdgcn_logf(prod) - (float)cnt*C_OUT;

    part[c*NPIX + t*64 + l] = acc;       // coalesced 256B row per wave
    if (t == 0 && blockIdx.y == 0 && threadIdx.x == 0) *out = 0.0f;
}

__global__ void __launch_bounds__(256)
loss_kernel(const float* __restrict__ part, const float* __restrict__ ref,
            const float* __restrict__ cam, float* __restrict__ out) {
    const int p = blockIdx.x * 256 + threadIdx.x;    // tile-swizzled pixel slot
    const int w = p >> 6, l = p & 63;
    const int x = (w % 24) * 8 + (l & 7);
    const int y = (w / 24) * 8 + (l >> 3);
    float S = 0.0f;
    #pragma unroll
    for (int c = 0; c < NCH; ++c) S += part[c*NPIX + p];
    const float img = 1.0f - __builtin_amdgcn_exp2f(S);
    const float d = ref[y*WW + x] - img;
    float sq = d * d;
    #pragma unroll
    for (int off = 32; off > 0; off >>= 1)
        sq += __shfl_down(sq, off, 64);
    __shared__ float wsum[4];
    const int lane = threadIdx.x & 63, wave = threadIdx.x >> 6;
    if (lane == 0) wsum[wave] = sq;
    __syncthreads();
    if (threadIdx.x == 0) {
        const float cx = cam[0], cy = cam[1], cz = cam[2];
        const float nrm = sqrtf(cx*cx + cy*cy + cz*cz);
        const float factor = 1.0f + fmaxf(6.0f - nrm, 0.0f);
        atomicAdd(out, (wsum[0] + wsum[1] + wsum[2] + wsum[3]) * factor);
    }
}

extern "C" void kernel_launch(void* const* d_in, const int* in_sizes, int n_in,
                              void* d_out, int out_size, void* d_ws, size_t ws_size,
                              hipStream_t stream) {
    const float* verts = (const float*)d_in[0];   // (1,1024,3) f32
    const int*   faces = (const int*)d_in[1];     // (1,2048,3) i32
    const float* ref   = (const float*)d_in[2];   // (192,192) f32
    const float* cam   = (const float*)d_in[3];   // (3,) f32
    float* out  = (float*)d_out;
    float* part = (float*)d_ws;                   // NCH * NPIX floats

    main_kernel<<<dim3(NTILE, 8), 256, 0, stream>>>(verts, faces, cam, part, out);
    loss_kernel<<<NPIX/256, 256, 0, stream>>>(part, ref, cam, out);
}

// Round 7
// 83.234 us; speedup vs baseline: 1.4015x; 1.1023x over previous
//
#include <hip/hip_runtime.h>

#define HH 192
#define WW 192
#define VV 1024
#define FF 2048
#define NPIX (HH*WW)
#define SIG 0.01f
#define EPSF 1e-7f
#define LOG2E 1.4426950408889634f
#define SKIP_T 12.5f                 // tile beyond one edge by this -> skip (err 2^-12.5/pair)
#define DEEP_T 11.0f                 // tile deep inside all edges -> C_IN (img err 2^-11/pair)
#define C_OUT 1.4426943e-7f          // log2(1+EPSF)
#define C_IN  (-23.2534966642f)      // log2(EPSF)
#define NTILE 576                    // 24x24 tiles of 8x8 px

#if defined(__has_builtin)
#if __has_builtin(__builtin_amdgcn_fdot2)
#define USE_DOT2 1
#endif
#endif

typedef _Float16 h2 __attribute__((ext_vector_type(2)));

// ws layout (floats):
// [0, NPIX)            logmiss, tile-swizzled: p = tile*64 + lane
// [NPIX, NPIX+9*FF)    coeffs SoA: coeffs[e*FF + f], e in 0..8
//                      arg_i = A_i*py + B_i*px + C_i; order A0 B0 C0 A1 B1 C1 A2 B2 C2
// [NPIX+9*FF]          loss scale factor

__global__ void __launch_bounds__(256)
prep_kernel(const float* __restrict__ verts, const int* __restrict__ faces,
            const float* __restrict__ cam, float* __restrict__ coeffs,
            float* __restrict__ logmiss, float* __restrict__ factor_out,
            float* __restrict__ out) {
    const int b = blockIdx.x, tid = threadIdx.x;
    if (b < NPIX / 256) {               // 144 blocks: zero logmiss
        logmiss[b * 256 + tid] = 0.0f;
        return;
    }
    // b in 144..151: coefficient blocks, 256 faces each
    __shared__ float sx[VV], sy[VV];
    const float cx = cam[0], cy = cam[1], cz = cam[2];
    const float nrm = sqrtf(cx*cx + cy*cy + cz*cz);
    const float inv = 1.0f / fmaxf(nrm, 1e-8f);
    const float zx = -cx*inv, zy = -cy*inv, zz = -cz*inv;
    float xx = zz, xz = -zx;
    const float invx = 1.0f / fmaxf(sqrtf(xx*xx + xz*xz), 1e-8f);
    xx *= invx; xz *= invx;
    const float yx = zy*xz, yy = zz*xx - zx*xz, yz = -zy*xx;
    const float ratio = 0.57735026918962576f;   // tan(30 deg)

    for (int i = tid; i < VV; i += 256) {
        const float vx = verts[3*i+0] - cx;
        const float vy = verts[3*i+1] - cy;
        const float vz = verts[3*i+2] - cz;
        const float pcx = xx*vx + xz*vz;
        const float pcy = yx*vx + yy*vy + yz*vz;
        float pcz = zx*vx + zy*vy + zz*vz;
        pcz = fmaxf(pcz, 1e-5f);
        const float iz = 1.0f / (pcz * ratio);
        sx[i] = pcx * iz;
        sy[i] = pcy * iz;
    }
    __syncthreads();

    const int f = (b - 144) * 256 + tid;
    const int i0 = faces[3*f+0], i1 = faces[3*f+1], i2 = faces[3*f+2];
    const float p0x = sx[i0], p0y = sy[i0];
    const float p1x = sx[i1], p1y = sy[i1];
    const float p2x = sx[i2], p2y = sy[i2];
    const float e0x = p1x-p0x, e0y = p1y-p0y;
    const float e1x = p2x-p1x, e1y = p2y-p1y;
    const float e2x = p0x-p2x, e2y = p0y-p2y;
    const float c0 = e0y*p0x - e0x*p0y;
    const float c1 = e1y*p1x - e1x*p1y;
    const float c2 = e2y*p2x - e2x*p2y;
    const float area2 = e0x*(p2y-p0y) - e0y*(p2x-p0x);
    const float sgn = (area2 >= 0.0f) ? 1.0f : -1.0f;
    const float l0 = fmaxf(sqrtf(e0x*e0x + e0y*e0y), 1e-8f);
    const float l1 = fmaxf(sqrtf(e1x*e1x + e1y*e1y), 1e-8f);
    const float l2 = fmaxf(sqrtf(e2x*e2x + e2y*e2y), 1e-8f);
    const float m0 = -sgn * (LOG2E/SIG) / l0;
    const float m1 = -sgn * (LOG2E/SIG) / l1;
    const float m2 = -sgn * (LOG2E/SIG) / l2;
    coeffs[0*FF+f] = m0*e0x;  coeffs[1*FF+f] = -m0*e0y;  coeffs[2*FF+f] = m0*c0;
    coeffs[3*FF+f] = m1*e1x;  coeffs[4*FF+f] = -m1*e1y;  coeffs[5*FF+f] = m1*c1;
    coeffs[6*FF+f] = m2*e2x;  coeffs[7*FF+f] = -m2*e2y;  coeffs[8*FF+f] = m2*c2;

    if (b == 144 && tid == 0) {
        const float dist = sqrtf(cx*cx + cy*cy + cz*cz);
        *factor_out = 1.0f + fmaxf(6.0f - dist, 0.0f);
        *out = 0.0f;
    }
}

// One wave = one (tile, 64-face chunk). 18432 waves, no tail.
__global__ void __launch_bounds__(256)
main_kernel(const float* __restrict__ coeffs, float* __restrict__ logmiss) {
    const int t = blockIdx.x;                        // tile 0..575
    const int w = threadIdx.x >> 6, l = threadIdx.x & 63;
    const int c = blockIdx.y * 4 + w;                // chunk 0..31
    const int f = c * 64 + l;                        // this lane's face

    const int tx = t % 24, ty = t / 24;
    const int x = tx*8 + (l & 7), y = ty*8 + (l >> 3);
    const float px = (x + 0.5f) * (2.0f/WW) - 1.0f;
    const float py = 1.0f - (y + 0.5f) * (2.0f/HH);
    const float xc = (tx*8 + 4.0f) * (2.0f/WW) - 1.0f;
    const float yc = 1.0f - (ty*8 + 4.0f) * (2.0f/HH);
    const float hx = 3.5f * (2.0f/WW), hy = 3.5f * (2.0f/HH);

    // lane-parallel coalesced load + f32 interval classification of 64 faces
    const float A0 = coeffs[0*FF+f], B0 = coeffs[1*FF+f], C0 = coeffs[2*FF+f];
    const float A1 = coeffs[3*FF+f], B1 = coeffs[4*FF+f], C1 = coeffs[5*FF+f];
    const float A2 = coeffs[6*FF+f], B2 = coeffs[7*FF+f], C2 = coeffs[8*FF+f];
    const float ac0 = fmaf(A0, yc, fmaf(B0, xc, C0));
    const float ac1 = fmaf(A1, yc, fmaf(B1, xc, C1));
    const float ac2 = fmaf(A2, yc, fmaf(B2, xc, C2));
    const float sp0 = fmaf(fabsf(A0), hy, fabsf(B0)*hx);
    const float sp1 = fmaf(fabsf(A1), hy, fabsf(B1)*hx);
    const float sp2 = fmaf(fabsf(A2), hy, fabsf(B2)*hx);
    const bool skip = (ac0 - sp0 >= SKIP_T) || (ac1 - sp1 >= SKIP_T) || (ac2 - sp2 >= SKIP_T);
    const bool deep = (ac0 + sp0 <= -DEEP_T) && (ac1 + sp1 <= -DEEP_T) && (ac2 + sp2 <= -DEEP_T);

    float acc = 64.0f * C_OUT
              + (float)__popcll(__ballot(deep)) * (C_IN - C_OUT);
    unsigned long long mb = __ballot(!skip && !deep);

#ifdef USE_DOT2
    // pack this lane's edge gradients once (used when broadcast to the wave)
    const h2 ab0 = { (_Float16)A0, (_Float16)B0 };
    const h2 ab1 = { (_Float16)A1, (_Float16)B1 };
    const h2 ab2 = { (_Float16)A2, (_Float16)B2 };
    const int pk0 = __builtin_bit_cast(int, ab0);
    const int pk1 = __builtin_bit_cast(int, ab1);
    const int pk2 = __builtin_bit_cast(int, ab2);
    const h2 dyx = { (_Float16)(py - yc), (_Float16)(px - xc) };
#endif

    float prod = 1.0f;
    int cnt = 0;
    while (mb) {                         // wave-uniform loop over band faces
        const int src = __builtin_ctzll(mb); mb &= mb - 1;
#ifdef USE_DOT2
        const h2 b0 = __builtin_bit_cast(h2, __builtin_amdgcn_readlane(pk0, src));
        const h2 b1 = __builtin_bit_cast(h2, __builtin_amdgcn_readlane(pk1, src));
        const h2 b2 = __builtin_bit_cast(h2, __builtin_amdgcn_readlane(pk2, src));
#define RL(v) __int_as_float(__builtin_amdgcn_readlane(__float_as_int(v), src))
        const float a0 = __builtin_amdgcn_fdot2(b0, dyx, RL(ac0), false);
        const float a1 = __builtin_amdgcn_fdot2(b1, dyx, RL(ac1), false);
        const float a2 = __builtin_amdgcn_fdot2(b2, dyx, RL(ac2), false);
#undef RL
#else
#define RL(v) __int_as_float(__builtin_amdgcn_readlane(__float_as_int(v), src))
        const float a0 = fmaf(RL(A0), py, fmaf(RL(B0), px, RL(C0)));
        const float a1 = fmaf(RL(A1), py, fmaf(RL(B1), px, RL(C1)));
        const float a2 = fmaf(RL(A2), py, fmaf(RL(B2), px, RL(C2)));
#undef RL
#endif
        const float t0 = __builtin_amdgcn_exp2f(a0);
        const float t1 = __builtin_amdgcn_exp2f(a1);
        const float t2 = __builtin_amdgcn_exp2f(a2);
        const float Pr = (1.0f + t0) * (1.0f + t1) * (1.0f + t2);
        prod *= (1.0f + EPSF) - __builtin_amdgcn_rcpf(Pr);   // in [eps, 1+eps]
        if (++cnt == 4) {                // batched log2 (prod >= 1e-28, normal)
            acc += __builtin_amdgcn_logf(prod) - 4.0f*C_OUT;
            prod = 1.0f; cnt = 0;
        }
    }
    if (cnt) acc += __builtin_amdgcn_logf(prod) - (float)cnt*C_OUT;

    atomicAdd(&logmiss[t*64 + l], acc);
}

__global__ void __launch_bounds__(256)
loss_kernel(const float* __restrict__ logmiss, const float* __restrict__ ref,
            const float* __restrict__ factor, float* __restrict__ out) {
    const int p = blockIdx.x * 256 + threadIdx.x;
    const int w = p >> 6, l = p & 63;
    const int x = (w % 24) * 8 + (l & 7);
    const int y = (w / 24) * 8 + (l >> 3);
    const float s = logmiss[p];
    const float image = 1.0f - __builtin_amdgcn_exp2f(s);
    const float d = ref[y*WW + x] - image;
    float sq = d * d;
    #pragma unroll
    for (int off = 32; off > 0; off >>= 1)
        sq += __shfl_down(sq, off, 64);
    __shared__ float wsum[4];
    const int lane = threadIdx.x & 63, wave = threadIdx.x >> 6;
    if (lane == 0) wsum[wave] = sq;
    __syncthreads();
    if (threadIdx.x == 0) {
        const float tot = (wsum[0] + wsum[1] + wsum[2] + wsum[3]) * factor[0];
        atomicAdd(out, tot);
    }
}

extern "C" void kernel_launch(void* const* d_in, const int* in_sizes, int n_in,
                              void* d_out, int out_size, void* d_ws, size_t ws_size,
                              hipStream_t stream) {
    const float* verts = (const float*)d_in[0];   // (1,1024,3) f32
    const int*   faces = (const int*)d_in[1];     // (1,2048,3) i32
    const float* ref   = (const float*)d_in[2];   // (192,192) f32
    const float* cam   = (const float*)d_in[3];   // (3,) f32
    float* out = (float*)d_out;

    float* ws      = (float*)d_ws;
    float* logmiss = ws;                           // NPIX
    float* coeffs  = ws + NPIX;                    // 9*FF
    float* factor  = ws + NPIX + 9*FF;             // 1

    prep_kernel<<<152, 256, 0, stream>>>(verts, faces, cam, coeffs,
                                         logmiss, factor, out);
    main_kernel<<<dim3(NTILE, 8), 256, 0, stream>>>(coeffs, logmiss);
    loss_kernel<<<NPIX/256, 256, 0, stream>>>(logmiss, ref, factor, out);
}